// Round 11
// baseline (8794.845 us; speedup 1.0000x reference)
//
#include <hip/hip_runtime.h>
#include <hip/hip_bf16.h>

#define BS_   2048
#define HID_  512
#define PH_   32
#define GRP_  16        // blocks per sync group

typedef _Float16 half8 __attribute__((ext_vector_type(8)));
typedef float floatx4 __attribute__((ext_vector_type(4)));

__device__ __forceinline__ float sigf(float x) { return 1.f / (1.f + __expf(-x)); }
__device__ __forceinline__ float tanhfast(float x) {
    float e = __expf(2.f * x);          // e=inf -> 1, e->0 -> -1 : safe at extremes
    return 1.f - 2.f / (e + 1.f);
}

// ---------------------------------------------------------------------------
// Prep: fp16 weights (W_ih, W_ih+W_hh), combined bias, z16, zero the flag
// words. Flags: one int per (ib, t), padded to a 64B line each:
// cnt[(ib*32 + t)*16], 512 * 16 = 8192 ints = 32 KB.
// ---------------------------------------------------------------------------
__global__ __launch_bounds__(256) void prep_kernel(
    const float* __restrict__ Wih, const float* __restrict__ Whh,
    const float* __restrict__ bih, const float* __restrict__ bhh,
    const float* __restrict__ z,
    _Float16* __restrict__ wih16, _Float16* __restrict__ wsum16,
    _Float16* __restrict__ z16, float* __restrict__ bsum,
    int* __restrict__ cnt)
{
    int i = blockIdx.x * 256 + threadIdx.x;          // [0, 1048576)
    if (i < BS_ * HID_) z16[i] = (_Float16)z[i];
    if (i < 4 * HID_ * HID_) {
        float a = Wih[i];
        wih16[i]  = (_Float16)a;
        wsum16[i] = (_Float16)(a + Whh[i]);
    }
    if (i < 4 * HID_) bsum[i] = bih[i] + bhh[i];
    if (i < 8192) cnt[i] = 0;
}

// ---------------------------------------------------------------------------
// Stage a 32-hid weight slice: 128 gate rows x 512 K fp16 = 128 KB LDS,
// XOR-swizzled on 16B blocks.
// ---------------------------------------------------------------------------
__device__ __forceinline__ void stage_weights(_Float16* Wl, const _Float16* Wg,
                                              int j, int tid)
{
#pragma unroll
    for (int rep = 0; rep < 16; ++rep) {
        int idx = rep * 512 + tid;      // [0, 8192): row n in [0,128), kb in [0,64)
        int n  = idx >> 6;
        int kb = idx & 63;
        int g  = n >> 5, u = n & 31;    // gate, hid-within-slice
        const half8* src = (const half8*)(Wg + ((size_t)(g * HID_ + j * 32 + u)) * HID_ + kb * 8);
        int phys = (kb & 56) | ((kb & 7) ^ (n & 7));
        *(half8*)((char*)Wl + n * 1024 + phys * 16) = *src;
    }
}

// ---------------------------------------------------------------------------
// Persistent LSTM with CHUNKED consumption (R9 chassis otherwise).
// Grid = 256 x 512. ib = blockIdx & 15 (128-row batch tile), j = blockIdx>>4
// (32 hid units = 128 gate rows, 128 KB LDS, restaged once at the t=0 tail).
// Wave wv: M-strip (wv&3)*32 rows, hid-half wv>>2.
//
// K-chunk kk of the gate GEMM consumes h[t-1] cols [32kk,32kk+32) -- produced
// exactly by block (ib, kk). Producer signal: post-epilogue __syncthreads
// (drains all waves' agent-scope WT h-stores at the CP -- R6/R9-proven) ->
// tid0 fetch_or(1<<j) into the (ib,t) flag word. Consumer waves free-run:
// own chunk j is barrier-guaranteed (no flag needed); the rest are consumed
// in readiness order via a 2-deep prefetch queue (A global + B LDS issued at
// push time), topped up by whole-wave relaxed CP-RMW polls (lane0 + shfl;
// plain loads go stale -- R2). Polls are bounded (~2-4/wave/step), NOT a
// continuous spin (R7/R8's 4-5x poll-storm regression -- do not re-attempt).
// The fan-in skew + flag-visibility latency hide behind the other chunks'
// MFMA work. One block barrier per step (producer drain); consumer barrier
// deleted. XCD-locality gating abandoned (failed to engage 3x: R4/R5/R10).
// ---------------------------------------------------------------------------
__global__ __launch_bounds__(512) void lstm_persist(
    const _Float16* __restrict__ wih16, const _Float16* __restrict__ wsum16,
    const float* __restrict__ bsum, const _Float16* __restrict__ z16,
    _Float16* __restrict__ hs, int* __restrict__ cnt)
{
    __shared__ _Float16 Wl[128 * 512];   // 128 KB

    const int tid  = threadIdx.x;
    const int ib   = blockIdx.x & 15;
    const int j    = blockIdx.x >> 4;
    const int lane = tid & 63;
    const int wv   = tid >> 6;
    const int ms   = wv & 3;            // M-strip: 32 rows of the 128-row tile
    const int hh   = wv >> 2;           // hid half: 0 -> units 0..15, 1 -> 16..31
    const int qw   = lane >> 4;         // quad 0..3
    const int ln   = lane & 15;
    const int hid  = j * 32 + hh * 16 + ln;

    stage_weights(Wl, wih16, j, tid);

    float bias[4];
#pragma unroll
    for (int g = 0; g < 4; ++g) bias[g] = bsum[g * HID_ + hid];

    float c[2][4];
#pragma unroll
    for (int mt = 0; mt < 2; ++mt)
#pragma unroll
        for (int r = 0; r < 4; ++r) c[mt][r] = 0.f;

    const char* Bl = (const char*)Wl;
    const int tE = (qw ^ (ln & 7)) * 16;    // swizzled byte offset, kk-even
    const int rowB = hh * 16 + ln;          // LDS row within a gate's 32 rows

    __syncthreads();

    for (int t = 0; t < PH_; ++t) {
        const _Float16* xx = (t == 0) ? z16 : hs + (size_t)(t - 1) * BS_ * HID_;
        int* flw = &cnt[(ib * 32 + (t > 0 ? t - 1 : 0)) * 16];

        floatx4 acc[2][4];                  // bias pre-folded
#pragma unroll
        for (int mt = 0; mt < 2; ++mt)
#pragma unroll
            for (int g = 0; g < 4; ++g)
                acc[mt][g] = (floatx4){bias[g], bias[g], bias[g], bias[g]};

        // A base: A[m = ln][k = qw*8 + jj] per chunk
        const _Float16* A0 = xx + (size_t)(ib * 128 + ms * 32 + ln) * HID_ + qw * 8;

        // ---- chunked K-loop with 2-deep readiness-ordered prefetch queue ----
        unsigned rdy = (t == 0) ? 0xFFFFu : 0u;  // t=0: z16 fully available
        unsigned rem = 0xFFFFu & ~(1u << j);     // own chunk seeded below
        int   sc[2];
        half8 sa0[2], sa1[2], sb[2][4];

        // seed slot 0 with own chunk (barrier-guaranteed ready)
        sc[0] = j;
        sa0[0] = *(const half8*)(A0 + j * 32);
        sa1[0] = *(const half8*)(A0 + 16 * HID_ + j * 32);
#pragma unroll
        for (int g = 0; g < 4; ++g)
            sb[0][g] = *(const half8*)(Bl + (g * 32 + rowB) * 1024
                                          + (j >> 1) * 128 + (tE ^ ((j & 1) << 6)));
        int ns = 1;

        for (int i = 0; i < 16; ++i) {
            // top up the queue to depth 2 (block only if empty)
            while (ns < 2 && rem) {
                unsigned av = rdy & rem;
                if (!av) {
                    if (ns >= 1) break;     // keep computing with depth 1
                    int v = 0;
                    if (lane == 0)
                        v = __hip_atomic_fetch_add(flw, 0, __ATOMIC_RELAXED,
                                                   __HIP_MEMORY_SCOPE_AGENT);
                    v = __shfl(v, 0);
                    rdy = (unsigned)v;
                    if (!(rdy & rem)) { __builtin_amdgcn_s_sleep(1); continue; }
                    av = rdy & rem;
                }
                int nk = __ffs(av) - 1;
                rem &= ~(1u << nk);
                sc[ns] = nk;
                sa0[ns] = *(const half8*)(A0 + nk * 32);
                sa1[ns] = *(const half8*)(A0 + 16 * HID_ + nk * 32);
#pragma unroll
                for (int g = 0; g < 4; ++g)
                    sb[ns][g] = *(const half8*)(Bl + (g * 32 + rowB) * 1024
                                                   + (nk >> 1) * 128 + (tE ^ ((nk & 1) << 6)));
                ++ns;
            }
            // consume slot 0
            half8 ca0 = sa0[0], ca1 = sa1[0];
            half8 cb0 = sb[0][0], cb1 = sb[0][1], cb2 = sb[0][2], cb3 = sb[0][3];
            sc[0] = sc[1]; sa0[0] = sa0[1]; sa1[0] = sa1[1];
#pragma unroll
            for (int g = 0; g < 4; ++g) sb[0][g] = sb[1][g];
            --ns;

            acc[0][0] = __builtin_amdgcn_mfma_f32_16x16x32_f16(ca0, cb0, acc[0][0], 0, 0, 0);
            acc[1][0] = __builtin_amdgcn_mfma_f32_16x16x32_f16(ca1, cb0, acc[1][0], 0, 0, 0);
            acc[0][1] = __builtin_amdgcn_mfma_f32_16x16x32_f16(ca0, cb1, acc[0][1], 0, 0, 0);
            acc[1][1] = __builtin_amdgcn_mfma_f32_16x16x32_f16(ca1, cb1, acc[1][1], 0, 0, 0);
            acc[0][2] = __builtin_amdgcn_mfma_f32_16x16x32_f16(ca0, cb2, acc[0][2], 0, 0, 0);
            acc[1][2] = __builtin_amdgcn_mfma_f32_16x16x32_f16(ca1, cb2, acc[1][2], 0, 0, 0);
            acc[0][3] = __builtin_amdgcn_mfma_f32_16x16x32_f16(ca0, cb3, acc[0][3], 0, 0, 0);
            acc[1][3] = __builtin_amdgcn_mfma_f32_16x16x32_f16(ca1, cb3, acc[1][3], 0, 0, 0);
        }

        // epilogue: C/D layout col=ln, row=qw*4+r; all 4 gates in-thread.
        // h stores agent-scope write-through (coherence point), R6/R9-proven.
        _Float16* hb = hs + (size_t)t * BS_ * HID_
                          + (size_t)(ib * 128 + ms * 32 + qw * 4) * HID_ + hid;
#pragma unroll
        for (int mt = 0; mt < 2; ++mt) {
#pragma unroll
            for (int r = 0; r < 4; ++r) {
                float gi = acc[mt][0][r];
                float gf = acc[mt][1][r];
                float gg = acc[mt][2][r];
                float go = acc[mt][3][r];
                float cn = sigf(gf) * c[mt][r] + sigf(gi) * tanhfast(gg);
                float hn = sigf(go) * tanhfast(cn);
                c[mt][r] = cn;
                _Float16 hf = (_Float16)hn;
                short hv;
                __builtin_memcpy(&hv, &hf, 2);
                __hip_atomic_store((short*)(hb + (size_t)(mt * 16 + r) * HID_), hv,
                                   __ATOMIC_RELAXED, __HIP_MEMORY_SCOPE_AGENT);
            }
        }

        // Barrier drains every wave's WT stores (vmcnt(0) -> CP-acked), then
        // ONE fetch_or publishes this block's chunk bit for step t.
        __syncthreads();
        if (t == 0) {
            if (tid == 0)
                __hip_atomic_fetch_or(&cnt[(ib * 32) * 16], 1 << j,
                                      __ATOMIC_RELAXED, __HIP_MEMORY_SCOPE_AGENT);
            stage_weights(Wl, wsum16, j, tid);   // switch to W_ih+W_hh (once)
            __syncthreads();
        } else if (t < PH_ - 1) {
            if (tid == 0)
                __hip_atomic_fetch_or(&cnt[(ib * 32 + t) * 16], 1 << j,
                                      __ATOMIC_RELAXED, __HIP_MEMORY_SCOPE_AGENT);
        }
    }
}

// ---------------------------------------------------------------------------
// y[b,t,:] = hs[t][b,:] @ W_d^T + b_d. One wave per (b,t) row.
// ---------------------------------------------------------------------------
__global__ __launch_bounds__(256) void dense_kernel(
    const _Float16* __restrict__ hs, const float* __restrict__ Wd,
    const float* __restrict__ bd, float* __restrict__ y)
{
    int gw   = (blockIdx.x * 256 + threadIdx.x) >> 6;   // wave id [0, 65536)
    int lane = threadIdx.x & 63;
    int tt = gw & 31, b = gw >> 5;
    half8 h = *(const half8*)(hs + ((size_t)tt * BS_ + b) * HID_ + lane * 8);
    float s0 = 0.f, s1 = 0.f;
#pragma unroll
    for (int k = 0; k < 8; ++k) {
        float hv = (float)h[k];
        s0 += hv * Wd[lane * 8 + k];
        s1 += hv * Wd[HID_ + lane * 8 + k];
    }
#pragma unroll
    for (int m = 32; m >= 1; m >>= 1) {
        s0 += __shfl_xor(s0, m);
        s1 += __shfl_xor(s1, m);
    }
    if (lane == 0) {
        float* o = y + ((size_t)b * PH_ + tt) * 2;
        o[0] = s0 + bd[0];
        o[1] = s1 + bd[1];
    }
}

// ---------------------------------------------------------------------------
extern "C" void kernel_launch(void* const* d_in, const int* in_sizes, int n_in,
                              void* d_out, int out_size, void* d_ws, size_t ws_size,
                              hipStream_t stream)
{
    (void)in_sizes; (void)n_in; (void)out_size; (void)ws_size;
    // setup_inputs order: hist(0, unused), z(1), W_ih(2), W_hh(3), b_ih(4),
    //                     b_hh(5), W_d(6), b_d(7)
    const float* z   = (const float*)d_in[1];
    const float* Wih = (const float*)d_in[2];
    const float* Whh = (const float*)d_in[3];
    const float* bih = (const float*)d_in[4];
    const float* bhh = (const float*)d_in[5];
    const float* Wd  = (const float*)d_in[6];
    const float* bd  = (const float*)d_in[7];
    float* y = (float*)d_out;

    char* ws = (char*)d_ws;
    _Float16* hs     = (_Float16*)ws;                          // 64 MB
    _Float16* z16    = (_Float16*)(ws + (size_t)67108864);     // 2 MB
    _Float16* wih16  = (_Float16*)(ws + (size_t)69206016);     // 2 MB
    _Float16* wsum16 = (_Float16*)(ws + (size_t)71303168);     // 2 MB
    float*    bsum   = (float*)   (ws + (size_t)73400320);     // 8 KB
    int*      cnt    = (int*)     (ws + (size_t)73408512);     // 8192 ints (32 KB)

    prep_kernel<<<4096, 256, 0, stream>>>(Wih, Whh, bih, bhh, z,
                                          wih16, wsum16, z16, bsum, cnt);

    {
        const void* k = (const void*)lstm_persist;
        void* args[] = {(void*)&wih16, (void*)&wsum16, (void*)&bsum,
                        (void*)&z16, (void*)&hs, (void*)&cnt};
        hipLaunchCooperativeKernel(k, dim3(256), dim3(512), args, 0, stream);
    }

    dense_kernel<<<16384, 256, 0, stream>>>(hs, Wd, bd, y);
}

// Round 12
// 433.968 us; speedup vs baseline: 20.2661x; 20.2661x over previous
//
#include <hip/hip_runtime.h>
#include <hip/hip_bf16.h>

#define BS_   2048
#define HID_  512
#define PH_   32
#define GRP_  16        // blocks per sync group

typedef _Float16 half8 __attribute__((ext_vector_type(8)));
typedef float floatx4 __attribute__((ext_vector_type(4)));

__device__ __forceinline__ float sigf(float x) { return 1.f / (1.f + __expf(-x)); }
__device__ __forceinline__ float tanhfast(float x) {
    float e = __expf(2.f * x);          // e=inf -> 1, e->0 -> -1 : safe at extremes
    return 1.f - 2.f / (e + 1.f);
}

// ---------------------------------------------------------------------------
// Prep: fp16 weights (W_ih, W_ih+W_hh), combined bias, z16, zero the flag
// slots: flags[ib][j] at cnt[(ib*16 + j)*16] -- one 64B line per producer,
// 16*16*16 = 4096 ints.
// ---------------------------------------------------------------------------
__global__ __launch_bounds__(256) void prep_kernel(
    const float* __restrict__ Wih, const float* __restrict__ Whh,
    const float* __restrict__ bih, const float* __restrict__ bhh,
    const float* __restrict__ z,
    _Float16* __restrict__ wih16, _Float16* __restrict__ wsum16,
    _Float16* __restrict__ z16, float* __restrict__ bsum,
    int* __restrict__ cnt)
{
    int i = blockIdx.x * 256 + threadIdx.x;          // [0, 1048576)
    if (i < BS_ * HID_) z16[i] = (_Float16)z[i];
    if (i < 4 * HID_ * HID_) {
        float a = Wih[i];
        wih16[i]  = (_Float16)a;
        wsum16[i] = (_Float16)(a + Whh[i]);
    }
    if (i < 4 * HID_) bsum[i] = bih[i] + bhh[i];
    if (i < 4096) cnt[i] = 0;
}

// ---------------------------------------------------------------------------
// Stage a 32-hid weight slice: 128 gate rows x 512 K fp16 = 128 KB LDS,
// XOR-swizzled on 16B blocks.
// ---------------------------------------------------------------------------
__device__ __forceinline__ void stage_weights(_Float16* Wl, const _Float16* Wg,
                                              int j, int tid)
{
#pragma unroll
    for (int rep = 0; rep < 16; ++rep) {
        int idx = rep * 512 + tid;      // [0, 8192): row n in [0,128), kb in [0,64)
        int n  = idx >> 6;
        int kb = idx & 63;
        int g  = n >> 5, u = n & 31;    // gate, hid-within-slice
        const half8* src = (const half8*)(Wg + ((size_t)(g * HID_ + j * 32 + u)) * HID_ + kb * 8);
        int phys = (kb & 56) | ((kb & 7) ^ (n & 7));
        *(half8*)((char*)Wl + n * 1024 + phys * 16) = *src;
    }
}

// ---------------------------------------------------------------------------
// Persistent LSTM -- R9 chassis (best known: 335us), ONE delta: per-producer
// flag lines + parallel 16-lane poll (kills the 16-deep fan-in serialization
// on R9's shared counter line).
//
// Grid = 256 x 512. ib = blockIdx & 15 (128-row batch tile), j = blockIdx>>4
// (32 hid units = 128 gate rows, 128 KB LDS, restaged once at the t=0 tail).
// Wave wv: M-strip (wv&3)*32 rows, hid-half wv>>2.
//
// Sync: producer h stores are agent-scope write-through (CP, R6-proven);
// post-epilogue __syncthreads drains vmcnt; tid0 fetch_add(+1) on its OWN
// 64B flag line (uncontended -- flag value after step t is t+1). Consumer:
// wave 0 lanes 0..15 each poll one producer's line with a relaxed CP-RMW
// (16 independent in-flight atomics, one roundtrip; plain loads go stale --
// R2), __all-vote v >= t, then __syncthreads releases the block.
// Block-level only: per-wave polling regressed 4-27x (R7/R8/R11) -- never
// re-attempt. XCD-locality gating abandoned (failed 3x: R4/R5/R10).
// ---------------------------------------------------------------------------
__global__ __launch_bounds__(512) void lstm_persist(
    const _Float16* __restrict__ wih16, const _Float16* __restrict__ wsum16,
    const float* __restrict__ bsum, const _Float16* __restrict__ z16,
    _Float16* __restrict__ hs, int* __restrict__ cnt)
{
    __shared__ _Float16 Wl[128 * 512];   // 128 KB

    const int tid  = threadIdx.x;
    const int ib   = blockIdx.x & 15;
    const int j    = blockIdx.x >> 4;
    const int lane = tid & 63;
    const int wv   = tid >> 6;
    const int ms   = wv & 3;            // M-strip: 32 rows of the 128-row tile
    const int hh   = wv >> 2;           // hid half: 0 -> units 0..15, 1 -> 16..31
    const int qw   = lane >> 4;         // quad 0..3
    const int ln   = lane & 15;
    const int hid  = j * 32 + hh * 16 + ln;

    stage_weights(Wl, wih16, j, tid);

    float bias[4];
#pragma unroll
    for (int g = 0; g < 4; ++g) bias[g] = bsum[g * HID_ + hid];

    float c[2][4];
#pragma unroll
    for (int mt = 0; mt < 2; ++mt)
#pragma unroll
        for (int r = 0; r < 4; ++r) c[mt][r] = 0.f;

    const char* Bl = (const char*)Wl;
    const int tE = (qw ^ (ln & 7)) * 16;    // swizzled byte offset, kk-even
    const int rowB = hh * 16 + ln;          // LDS row within a gate's 32 rows

    __syncthreads();

    for (int t = 0; t < PH_; ++t) {
        const _Float16* xx = (t == 0) ? z16 : hs + (size_t)(t - 1) * BS_ * HID_;

        if (t >= 1) {
            if (wv == 0) {
                for (;;) {
                    int v = t;
                    if (lane < GRP_)
                        v = __hip_atomic_fetch_add(&cnt[(ib * 16 + lane) * 16], 0,
                                                   __ATOMIC_RELAXED,
                                                   __HIP_MEMORY_SCOPE_AGENT);
                    if (__all(v >= t)) break;
                    __builtin_amdgcn_s_sleep(1);
                }
            }
            __syncthreads();    // releases the block; orders loads after poll
        }

        floatx4 acc[2][4];                  // bias pre-folded
#pragma unroll
        for (int mt = 0; mt < 2; ++mt)
#pragma unroll
            for (int g = 0; g < 4; ++g)
                acc[mt][g] = (floatx4){bias[g], bias[g], bias[g], bias[g]};

        // A fragment: A[m = ln][k = qw*8 + jj]; depth-4 global prefetch ring
        const _Float16* A0 = xx + (size_t)(ib * 128 + ms * 32 + ln) * HID_ + qw * 8;

        half8 a0r[4], a1r[4], bA[4], bB[4];
#pragma unroll
        for (int p = 0; p < 4; ++p) {
            a0r[p] = *(const half8*)(A0 + p * 32);
            a1r[p] = *(const half8*)(A0 + 16 * HID_ + p * 32);
        }
#pragma unroll
        for (int g = 0; g < 4; ++g)
            bA[g] = *(const half8*)(Bl + (g * 32 + rowB) * 1024 + tE);

#pragma unroll
        for (int kk = 0; kk < 16; ++kk) {
            half8 ca0 = a0r[kk & 3], ca1 = a1r[kk & 3];
            if (kk < 12) {
                a0r[kk & 3] = *(const half8*)(A0 + (kk + 4) * 32);
                a1r[kk & 3] = *(const half8*)(A0 + 16 * HID_ + (kk + 4) * 32);
            }
            half8* cb = (kk & 1) ? bB : bA;
            half8* nb = (kk & 1) ? bA : bB;
            if (kk < 15) {
                int k1 = kk + 1;
#pragma unroll
                for (int g = 0; g < 4; ++g) {
                    int off = (g * 32 + rowB) * 1024 + (k1 >> 1) * 128 + (tE ^ ((k1 & 1) << 6));
                    nb[g] = *(const half8*)(Bl + off);
                }
            }
#pragma unroll
            for (int g = 0; g < 4; ++g) {
                acc[0][g] = __builtin_amdgcn_mfma_f32_16x16x32_f16(ca0, cb[g], acc[0][g], 0, 0, 0);
                acc[1][g] = __builtin_amdgcn_mfma_f32_16x16x32_f16(ca1, cb[g], acc[1][g], 0, 0, 0);
            }
        }

        // epilogue: C/D layout col=ln, row=qw*4+r; all 4 gates in-thread.
        // h stores agent-scope write-through (coherence point), R6/R9-proven.
        _Float16* hb = hs + (size_t)t * BS_ * HID_
                          + (size_t)(ib * 128 + ms * 32 + qw * 4) * HID_ + hid;
#pragma unroll
        for (int mt = 0; mt < 2; ++mt) {
#pragma unroll
            for (int r = 0; r < 4; ++r) {
                float gi = acc[mt][0][r];
                float gf = acc[mt][1][r];
                float gg = acc[mt][2][r];
                float go = acc[mt][3][r];
                float cn = sigf(gf) * c[mt][r] + sigf(gi) * tanhfast(gg);
                float hn = sigf(go) * tanhfast(cn);
                c[mt][r] = cn;
                _Float16 hf = (_Float16)hn;
                short hv;
                __builtin_memcpy(&hv, &hf, 2);
                __hip_atomic_store((short*)(hb + (size_t)(mt * 16 + r) * HID_), hv,
                                   __ATOMIC_RELAXED, __HIP_MEMORY_SCOPE_AGENT);
            }
        }

        // Barrier drains every wave's WT stores (vmcnt(0) -> CP-acked), then
        // ONE uncontended CP-RMW on this block's own flag line signals step t.
        __syncthreads();
        if (t == 0) {
            if (tid == 0)
                __hip_atomic_fetch_add(&cnt[(ib * 16 + j) * 16], 1,
                                       __ATOMIC_RELAXED, __HIP_MEMORY_SCOPE_AGENT);
            stage_weights(Wl, wsum16, j, tid);   // switch to W_ih+W_hh (once)
            __syncthreads();
        } else if (t < PH_ - 1) {
            if (tid == 0)
                __hip_atomic_fetch_add(&cnt[(ib * 16 + j) * 16], 1,
                                       __ATOMIC_RELAXED, __HIP_MEMORY_SCOPE_AGENT);
        }
    }
}

// ---------------------------------------------------------------------------
// y[b,t,:] = hs[t][b,:] @ W_d^T + b_d. One wave per (b,t) row.
// ---------------------------------------------------------------------------
__global__ __launch_bounds__(256) void dense_kernel(
    const _Float16* __restrict__ hs, const float* __restrict__ Wd,
    const float* __restrict__ bd, float* __restrict__ y)
{
    int gw   = (blockIdx.x * 256 + threadIdx.x) >> 6;   // wave id [0, 65536)
    int lane = threadIdx.x & 63;
    int tt = gw & 31, b = gw >> 5;
    half8 h = *(const half8*)(hs + ((size_t)tt * BS_ + b) * HID_ + lane * 8);
    float s0 = 0.f, s1 = 0.f;
#pragma unroll
    for (int k = 0; k < 8; ++k) {
        float hv = (float)h[k];
        s0 += hv * Wd[lane * 8 + k];
        s1 += hv * Wd[HID_ + lane * 8 + k];
    }
#pragma unroll
    for (int m = 32; m >= 1; m >>= 1) {
        s0 += __shfl_xor(s0, m);
        s1 += __shfl_xor(s1, m);
    }
    if (lane == 0) {
        float* o = y + ((size_t)b * PH_ + tt) * 2;
        o[0] = s0 + bd[0];
        o[1] = s1 + bd[1];
    }
}

// ---------------------------------------------------------------------------
extern "C" void kernel_launch(void* const* d_in, const int* in_sizes, int n_in,
                              void* d_out, int out_size, void* d_ws, size_t ws_size,
                              hipStream_t stream)
{
    (void)in_sizes; (void)n_in; (void)out_size; (void)ws_size;
    // setup_inputs order: hist(0, unused), z(1), W_ih(2), W_hh(3), b_ih(4),
    //                     b_hh(5), W_d(6), b_d(7)
    const float* z   = (const float*)d_in[1];
    const float* Wih = (const float*)d_in[2];
    const float* Whh = (const float*)d_in[3];
    const float* bih = (const float*)d_in[4];
    const float* bhh = (const float*)d_in[5];
    const float* Wd  = (const float*)d_in[6];
    const float* bd  = (const float*)d_in[7];
    float* y = (float*)d_out;

    char* ws = (char*)d_ws;
    _Float16* hs     = (_Float16*)ws;                          // 64 MB
    _Float16* z16    = (_Float16*)(ws + (size_t)67108864);     // 2 MB
    _Float16* wih16  = (_Float16*)(ws + (size_t)69206016);     // 2 MB
    _Float16* wsum16 = (_Float16*)(ws + (size_t)71303168);     // 2 MB
    float*    bsum   = (float*)   (ws + (size_t)73400320);     // 8 KB
    int*      cnt    = (int*)     (ws + (size_t)73408512);     // 4096 ints (16 KB)

    prep_kernel<<<4096, 256, 0, stream>>>(Wih, Whh, bih, bhh, z,
                                          wih16, wsum16, z16, bsum, cnt);

    {
        const void* k = (const void*)lstm_persist;
        void* args[] = {(void*)&wih16, (void*)&wsum16, (void*)&bsum,
                        (void*)&z16, (void*)&hs, (void*)&cnt};
        hipLaunchCooperativeKernel(k, dim3(256), dim3(512), args, 0, stream);
    }

    dense_kernel<<<16384, 256, 0, stream>>>(hs, Wd, bd, y);
}